// Round 1
// baseline (124.876 us; speedup 1.0000x reference)
//
#include <hip/hip_runtime.h>

#define D 128          // D_IN == EMBED == 128
#define NROWS 8192     // N_FIRMS

// K1: a[d] = sum_e Wv[e,d] * hw[e]  (a = Wv^T hw), and zero the b accumulator.
__global__ __launch_bounds__(128) void k1_prep(const float* __restrict__ Wv,
                                               const float* __restrict__ head_w,
                                               float* __restrict__ ws_a,
                                               float* __restrict__ ws_b) {
    const int t = threadIdx.x;  // 0..127
    float s0 = 0.f, s1 = 0.f, s2 = 0.f, s3 = 0.f;
#pragma unroll
    for (int e = 0; e < D; e += 4) {
        s0 += Wv[(e + 0) * D + t] * head_w[e + 0];
        s1 += Wv[(e + 1) * D + t] * head_w[e + 1];
        s2 += Wv[(e + 2) * D + t] * head_w[e + 2];
        s3 += Wv[(e + 3) * D + t] * head_w[e + 3];
    }
    ws_a[t] = (s0 + s1) + (s2 + s3);
    ws_b[t] = 0.f;  // zero accumulator (ws is poisoned 0xAA before every call)
}

// K2: fused y = X a  and  b = X^T y.
// One wave per row: lane l holds X[row, 2l..2l+1]; butterfly-sum the dot,
// then accumulate the outer product contribution into per-lane b registers.
__global__ __launch_bounds__(256) void k2_xa_xty(const float* __restrict__ X,
                                                 const float* __restrict__ ws_a,
                                                 float* __restrict__ ws_b) {
    const int lane = threadIdx.x & 63;
    const int wave = threadIdx.x >> 6;
    const int rowBase = blockIdx.x * 32 + wave * 8;
    const float2 a2 = *reinterpret_cast<const float2*>(ws_a + 2 * lane);
    float b0 = 0.f, b1 = 0.f;
#pragma unroll
    for (int r = 0; r < 8; ++r) {
        const int row = rowBase + r;
        const float2 x2 = *reinterpret_cast<const float2*>(X + row * D + 2 * lane);
        float p = x2.x * a2.x + x2.y * a2.y;
#pragma unroll
        for (int m = 32; m >= 1; m >>= 1) p += __shfl_xor(p, m, 64);
        // p == y[row] on every lane (bit-identical across lanes)
        b0 += x2.x * p;
        b1 += x2.y * p;
    }
    atomicAdd(&ws_b[2 * lane + 0], b0);
    atomicAdd(&ws_b[2 * lane + 1], b1);
}

// K4: c = Wk b ; w = Wq^T c.
__global__ __launch_bounds__(128) void k4_w(const float* __restrict__ Wk,
                                            const float* __restrict__ Wq,
                                            const float* __restrict__ ws_b,
                                            float* __restrict__ ws_w) {
    __shared__ float bs[D];
    __shared__ float cs[D];
    const int t = threadIdx.x;  // 0..127
    bs[t] = ws_b[t];
    __syncthreads();
    float s0 = 0.f, s1 = 0.f, s2 = 0.f, s3 = 0.f;
#pragma unroll
    for (int d = 0; d < D; d += 4) {
        s0 += Wk[t * D + d + 0] * bs[d + 0];
        s1 += Wk[t * D + d + 1] * bs[d + 1];
        s2 += Wk[t * D + d + 2] * bs[d + 2];
        s3 += Wk[t * D + d + 3] * bs[d + 3];
    }
    cs[t] = (s0 + s1) + (s2 + s3);
    __syncthreads();
    s0 = s1 = s2 = s3 = 0.f;
#pragma unroll
    for (int e = 0; e < D; e += 4) {
        s0 += Wq[(e + 0) * D + t] * cs[e + 0];
        s1 += Wq[(e + 1) * D + t] * cs[e + 1];
        s2 += Wq[(e + 2) * D + t] * cs[e + 2];
        s3 += Wq[(e + 3) * D + t] * cs[e + 3];
    }
    ws_w[t] = (s0 + s1) + (s2 + s3);
}

// K5: preds = X w + head_b. Same wave-per-row butterfly as K2.
__global__ __launch_bounds__(256) void k5_preds(const float* __restrict__ X,
                                                const float* __restrict__ ws_w,
                                                const float* __restrict__ head_b,
                                                float* __restrict__ out) {
    const int lane = threadIdx.x & 63;
    const int wave = threadIdx.x >> 6;
    const int rowBase = blockIdx.x * 32 + wave * 8;
    const float2 w2 = *reinterpret_cast<const float2*>(ws_w + 2 * lane);
    const float hb = head_b[0];
#pragma unroll
    for (int r = 0; r < 8; ++r) {
        const int row = rowBase + r;
        const float2 x2 = *reinterpret_cast<const float2*>(X + row * D + 2 * lane);
        float p = x2.x * w2.x + x2.y * w2.y;
#pragma unroll
        for (int m = 32; m >= 1; m >>= 1) p += __shfl_xor(p, m, 64);
        if (lane == 0) out[row] = p + hb;
    }
}

extern "C" void kernel_launch(void* const* d_in, const int* in_sizes, int n_in,
                              void* d_out, int out_size, void* d_ws, size_t ws_size,
                              hipStream_t stream) {
    const float* X      = (const float*)d_in[0];  // (8192,128)
    const float* Wq     = (const float*)d_in[1];  // (128,128)
    const float* Wk     = (const float*)d_in[2];  // (128,128)
    const float* Wv     = (const float*)d_in[3];  // (128,128)
    const float* head_w = (const float*)d_in[4];  // (1,128)
    const float* head_b = (const float*)d_in[5];  // (1,)
    float* out = (float*)d_out;                   // (8192,) f32

    float* ws   = (float*)d_ws;
    float* ws_a = ws;        // 128 f32
    float* ws_b = ws + 128;  // 128 f32 (atomic accumulator)
    float* ws_w = ws + 256;  // 128 f32

    k1_prep<<<1, 128, 0, stream>>>(Wv, head_w, ws_a, ws_b);
    k2_xa_xty<<<256, 256, 0, stream>>>(X, ws_a, ws_b);
    k4_w<<<1, 128, 0, stream>>>(Wk, Wq, ws_b, ws_w);
    k5_preds<<<256, 256, 0, stream>>>(X, ws_w, head_b, out);
}

// Round 3
// 76.639 us; speedup vs baseline: 1.6294x; 1.6294x over previous
//
#include <hip/hip_runtime.h>

#define D 128          // D_IN == EMBED == 128
#define NROWS 8192     // N_FIRMS
#define NBLK 256       // one block per CU
#define ROWS_PER_BLK (NROWS / NBLK)   // 32

// K2: fused  a = Wv^T hw ;  y = X a ;  partial[blk] = X_blk^T y_blk.
// 256 threads = 4 waves. Lane layout: half = lane>>5 selects row parity,
// l32 = lane&31 selects 4 consecutive columns (float4, 16 B/lane).
// Each wave covers 2 rows per load iteration; NO global atomics — each block
// writes one 128-float partial, reduced deterministically in k4.
__global__ __launch_bounds__(256) void k2_xa_xty(const float* __restrict__ X,
                                                 const float* __restrict__ Wv,
                                                 const float* __restrict__ head_w,
                                                 float* __restrict__ part) {
    __shared__ float a_s[D];
    __shared__ float red[4][D];
    const int t = threadIdx.x;

    // ---- phase A: a[d] = sum_e Wv[e,d] * hw[e] (threads 0..127) ----
    if (t < D) {
        float s0 = 0.f, s1 = 0.f, s2 = 0.f, s3 = 0.f;
#pragma unroll
        for (int e = 0; e < D; e += 4) {
            s0 += Wv[(e + 0) * D + t] * head_w[e + 0];
            s1 += Wv[(e + 1) * D + t] * head_w[e + 1];
            s2 += Wv[(e + 2) * D + t] * head_w[e + 2];
            s3 += Wv[(e + 3) * D + t] * head_w[e + 3];
        }
        a_s[t] = (s0 + s1) + (s2 + s3);
    }
    __syncthreads();

    // ---- phase B: stream 32 rows, accumulate outer product ----
    const int lane = t & 63;
    const int wave = t >> 6;
    const int half = lane >> 5;   // row parity within the wave's pair
    const int l32  = lane & 31;
    const int col  = l32 * 4;
    const float4 a4 = *reinterpret_cast<const float4*>(a_s + col);
    float4 b4 = make_float4(0.f, 0.f, 0.f, 0.f);
    const int rowBase = blockIdx.x * ROWS_PER_BLK + wave * 8 + half;
#pragma unroll
    for (int it = 0; it < 4; ++it) {
        const int row = rowBase + it * 2;
        const float4 x4 = *reinterpret_cast<const float4*>(X + row * D + col);
        float p = x4.x * a4.x + x4.y * a4.y + x4.z * a4.z + x4.w * a4.w;
#pragma unroll
        for (int m = 1; m <= 16; m <<= 1) p += __shfl_xor(p, m, 64);
        // p == y[row] across the 32-lane half
        b4.x += x4.x * p; b4.y += x4.y * p; b4.z += x4.z * p; b4.w += x4.w * p;
    }
    // fold the two halves (same columns, different rows)
    b4.x += __shfl_xor(b4.x, 32, 64);
    b4.y += __shfl_xor(b4.y, 32, 64);
    b4.z += __shfl_xor(b4.z, 32, 64);
    b4.w += __shfl_xor(b4.w, 32, 64);
    if (half == 0) *reinterpret_cast<float4*>(&red[wave][col]) = b4;
    __syncthreads();
    if (t < D)
        part[blockIdx.x * D + t] = (red[0][t] + red[1][t]) + (red[2][t] + red[3][t]);
}

// K4: b = column-sum(part) ; c = Wk b ; w = Wq^T c.
__global__ __launch_bounds__(128) void k4_w(const float* __restrict__ part,
                                            const float* __restrict__ Wk,
                                            const float* __restrict__ Wq,
                                            float* __restrict__ ws_w) {
    __shared__ float bs[D];
    __shared__ float cs[D];
    const int t = threadIdx.x;  // 0..127
    float s0 = 0.f, s1 = 0.f, s2 = 0.f, s3 = 0.f;
#pragma unroll 8
    for (int k = 0; k < NBLK; k += 4) {
        s0 += part[(k + 0) * D + t];
        s1 += part[(k + 1) * D + t];
        s2 += part[(k + 2) * D + t];
        s3 += part[(k + 3) * D + t];
    }
    bs[t] = (s0 + s1) + (s2 + s3);
    __syncthreads();
    s0 = s1 = s2 = s3 = 0.f;
#pragma unroll
    for (int d = 0; d < D; d += 4) {
        s0 += Wk[t * D + d + 0] * bs[d + 0];
        s1 += Wk[t * D + d + 1] * bs[d + 1];
        s2 += Wk[t * D + d + 2] * bs[d + 2];
        s3 += Wk[t * D + d + 3] * bs[d + 3];
    }
    cs[t] = (s0 + s1) + (s2 + s3);
    __syncthreads();
    s0 = s1 = s2 = s3 = 0.f;
#pragma unroll
    for (int e = 0; e < D; e += 4) {
        s0 += Wq[(e + 0) * D + t] * cs[e + 0];
        s1 += Wq[(e + 1) * D + t] * cs[e + 1];
        s2 += Wq[(e + 2) * D + t] * cs[e + 2];
        s3 += Wq[(e + 3) * D + t] * cs[e + 3];
    }
    ws_w[t] = (s0 + s1) + (s2 + s3);
}

// K5: preds = X w + head_b. Same float4 half-wave layout as k2 phase B.
__global__ __launch_bounds__(256) void k5_preds(const float* __restrict__ X,
                                                const float* __restrict__ ws_w,
                                                const float* __restrict__ head_b,
                                                float* __restrict__ out) {
    const int t = threadIdx.x;
    const int lane = t & 63;
    const int wave = t >> 6;
    const int half = lane >> 5;
    const int l32  = lane & 31;
    const int col  = l32 * 4;
    const float4 w4 = *reinterpret_cast<const float4*>(ws_w + col);
    const float hb = head_b[0];
    const int rowBase = blockIdx.x * ROWS_PER_BLK + wave * 8 + half;
#pragma unroll
    for (int it = 0; it < 4; ++it) {
        const int row = rowBase + it * 2;
        const float4 x4 = *reinterpret_cast<const float4*>(X + row * D + col);
        float p = x4.x * w4.x + x4.y * w4.y + x4.z * w4.z + x4.w * w4.w;
#pragma unroll
        for (int m = 1; m <= 16; m <<= 1) p += __shfl_xor(p, m, 64);
        if (l32 == 0) out[row] = p + hb;
    }
}

extern "C" void kernel_launch(void* const* d_in, const int* in_sizes, int n_in,
                              void* d_out, int out_size, void* d_ws, size_t ws_size,
                              hipStream_t stream) {
    const float* X      = (const float*)d_in[0];  // (8192,128)
    const float* Wq     = (const float*)d_in[1];  // (128,128)
    const float* Wk     = (const float*)d_in[2];  // (128,128)
    const float* Wv     = (const float*)d_in[3];  // (128,128)
    const float* head_w = (const float*)d_in[4];  // (1,128)
    const float* head_b = (const float*)d_in[5];  // (1,)
    float* out = (float*)d_out;                   // (8192,) f32

    float* ws      = (float*)d_ws;
    float* ws_part = ws;                 // 256*128 f32 = 128 KB
    float* ws_w    = ws + NBLK * D;      // 128 f32

    k2_xa_xty<<<NBLK, 256, 0, stream>>>(X, Wv, head_w, ws_part);
    k4_w<<<1, 128, 0, stream>>>(ws_part, Wk, Wq, ws_w);
    k5_preds<<<NBLK, 256, 0, stream>>>(X, ws_w, head_b, out);
}

// Round 4
// 75.795 us; speedup vs baseline: 1.6476x; 1.0111x over previous
//
#include <hip/hip_runtime.h>

#define D 128          // D_IN == EMBED == 128
#define NROWS 8192     // N_FIRMS
#define NBLK 256       // one block per CU
#define ROWS_PER_BLK (NROWS / NBLK)   // 32

// K2: fused  a = Wv^T hw ;  y = X a ;  partial[blk] = X_blk^T y_blk.
// 256 threads = 4 waves. Lane layout: half = lane>>5 selects row parity,
// l32 = lane&31 selects 4 consecutive columns (float4, 16 B/lane).
// No global atomics — each block writes one 128-float partial.
__global__ __launch_bounds__(256) void k2_xa_xty(const float* __restrict__ X,
                                                 const float* __restrict__ Wv,
                                                 const float* __restrict__ head_w,
                                                 float* __restrict__ part) {
    __shared__ float a_s[D];
    __shared__ float red[4][D];
    const int t = threadIdx.x;

    // ---- phase A: a[d] = sum_e Wv[e,d] * hw[e] (threads 0..127) ----
    if (t < D) {
        float s0 = 0.f, s1 = 0.f, s2 = 0.f, s3 = 0.f;
#pragma unroll
        for (int e = 0; e < D; e += 4) {
            s0 += Wv[(e + 0) * D + t] * head_w[e + 0];
            s1 += Wv[(e + 1) * D + t] * head_w[e + 1];
            s2 += Wv[(e + 2) * D + t] * head_w[e + 2];
            s3 += Wv[(e + 3) * D + t] * head_w[e + 3];
        }
        a_s[t] = (s0 + s1) + (s2 + s3);
    }
    __syncthreads();

    // ---- phase B: stream 32 rows, accumulate outer product ----
    const int lane = t & 63;
    const int wave = t >> 6;
    const int half = lane >> 5;
    const int l32  = lane & 31;
    const int col  = l32 * 4;
    const float4 a4 = *reinterpret_cast<const float4*>(a_s + col);
    float4 b4 = make_float4(0.f, 0.f, 0.f, 0.f);
    const int rowBase = blockIdx.x * ROWS_PER_BLK + wave * 8 + half;
#pragma unroll
    for (int it = 0; it < 4; ++it) {
        const int row = rowBase + it * 2;
        const float4 x4 = *reinterpret_cast<const float4*>(X + row * D + col);
        float p = x4.x * a4.x + x4.y * a4.y + x4.z * a4.z + x4.w * a4.w;
#pragma unroll
        for (int m = 1; m <= 16; m <<= 1) p += __shfl_xor(p, m, 64);
        // p == y[row] across the 32-lane half
        b4.x += x4.x * p; b4.y += x4.y * p; b4.z += x4.z * p; b4.w += x4.w * p;
    }
    b4.x += __shfl_xor(b4.x, 32, 64);
    b4.y += __shfl_xor(b4.y, 32, 64);
    b4.z += __shfl_xor(b4.z, 32, 64);
    b4.w += __shfl_xor(b4.w, 32, 64);
    if (half == 0) *reinterpret_cast<float4*>(&red[wave][col]) = b4;
    __syncthreads();
    if (t < D)
        part[blockIdx.x * D + t] = (red[0][t] + red[1][t]) + (red[2][t] + red[3][t]);
}

// K5: per block (redundantly, deterministic): b = colsum(part); c = Wk b;
// w = Wq^T c; then preds = X w + head_b for this block's 32 rows.
// part is 128 KB -> L3-broadcast to all 256 blocks (~32 MB aggregate, ~2 us).
__global__ __launch_bounds__(256) void k5_fused(const float* __restrict__ part,
                                                const float* __restrict__ Wk,
                                                const float* __restrict__ Wq,
                                                const float* __restrict__ X,
                                                const float* __restrict__ head_b,
                                                float* __restrict__ out) {
    __shared__ float bs[D];
    __shared__ float cs[D];
    __shared__ float w_s[D];
    const int t = threadIdx.x;

    // ---- b = column-sum over 256 block-partials (threads 0..127) ----
    if (t < D) {
        float s0 = 0.f, s1 = 0.f, s2 = 0.f, s3 = 0.f;
#pragma unroll 8
        for (int k = 0; k < NBLK; k += 4) {
            s0 += part[(k + 0) * D + t];
            s1 += part[(k + 1) * D + t];
            s2 += part[(k + 2) * D + t];
            s3 += part[(k + 3) * D + t];
        }
        bs[t] = (s0 + s1) + (s2 + s3);
    }
    __syncthreads();
    // ---- c = Wk b ----
    if (t < D) {
        float s0 = 0.f, s1 = 0.f, s2 = 0.f, s3 = 0.f;
#pragma unroll
        for (int d = 0; d < D; d += 4) {
            s0 += Wk[t * D + d + 0] * bs[d + 0];
            s1 += Wk[t * D + d + 1] * bs[d + 1];
            s2 += Wk[t * D + d + 2] * bs[d + 2];
            s3 += Wk[t * D + d + 3] * bs[d + 3];
        }
        cs[t] = (s0 + s1) + (s2 + s3);
    }
    __syncthreads();
    // ---- w = Wq^T c ----
    if (t < D) {
        float s0 = 0.f, s1 = 0.f, s2 = 0.f, s3 = 0.f;
#pragma unroll
        for (int e = 0; e < D; e += 4) {
            s0 += Wq[(e + 0) * D + t] * cs[e + 0];
            s1 += Wq[(e + 1) * D + t] * cs[e + 1];
            s2 += Wq[(e + 2) * D + t] * cs[e + 2];
            s3 += Wq[(e + 3) * D + t] * cs[e + 3];
        }
        w_s[t] = (s0 + s1) + (s2 + s3);
    }
    __syncthreads();

    // ---- preds for this block's 32 rows ----
    const int lane = t & 63;
    const int wave = t >> 6;
    const int half = lane >> 5;
    const int l32  = lane & 31;
    const int col  = l32 * 4;
    const float4 w4 = *reinterpret_cast<const float4*>(w_s + col);
    const float hb = head_b[0];
    const int rowBase = blockIdx.x * ROWS_PER_BLK + wave * 8 + half;
#pragma unroll
    for (int it = 0; it < 4; ++it) {
        const int row = rowBase + it * 2;
        const float4 x4 = *reinterpret_cast<const float4*>(X + row * D + col);
        float p = x4.x * w4.x + x4.y * w4.y + x4.z * w4.z + x4.w * w4.w;
#pragma unroll
        for (int m = 1; m <= 16; m <<= 1) p += __shfl_xor(p, m, 64);
        if (l32 == 0) out[row] = p + hb;
    }
}

extern "C" void kernel_launch(void* const* d_in, const int* in_sizes, int n_in,
                              void* d_out, int out_size, void* d_ws, size_t ws_size,
                              hipStream_t stream) {
    const float* X      = (const float*)d_in[0];  // (8192,128)
    const float* Wq     = (const float*)d_in[1];  // (128,128)
    const float* Wk     = (const float*)d_in[2];  // (128,128)
    const float* Wv     = (const float*)d_in[3];  // (128,128)
    const float* head_w = (const float*)d_in[4];  // (1,128)
    const float* head_b = (const float*)d_in[5];  // (1,)
    float* out = (float*)d_out;                   // (8192,) f32

    float* ws_part = (float*)d_ws;                // 256*128 f32 = 128 KB

    k2_xa_xty<<<NBLK, 256, 0, stream>>>(X, Wv, head_w, ws_part);
    k5_fused<<<NBLK, 256, 0, stream>>>(ws_part, Wk, Wq, X, head_b, out);
}